// Round 13
// baseline (335.647 us; speedup 1.0000x reference)
//
#include <hip/hip_runtime.h>
#include <hip/hip_bf16.h>
#include <cstdint>

#define SDIM 8192
#define DIN  4096
#define DOUT 4096
#define KAUG 4224   // 4096 + 8*16 LoRA extension
#define NADP 8
#define RLORA 16
#define NT 66       // K-tiles of 64

typedef __attribute__((ext_vector_type(8))) short short8;
typedef __attribute__((ext_vector_type(4))) float f32x4;
typedef __attribute__((ext_vector_type(16))) float f32x16;

// ---------- fused prep: x->bf16, W->bf16, B-tail, A->bf16 in ONE launch ----------
__global__ __launch_bounds__(256) void prep_all(const float* __restrict__ x,
                         const float* __restrict__ W,
                         const float* __restrict__ B0,
                         const float* __restrict__ A,
                         __hip_bfloat16* __restrict__ xaug,
                         __hip_bfloat16* __restrict__ waug,
                         __hip_bfloat16* __restrict__ abf) {
    int b = blockIdx.x;
    if (b < 24576) {   // x or W conversion
        const float* src = (b < 16384) ? x : W;
        __hip_bfloat16* dst = (b < 16384) ? xaug : waug;
        long base = (b < 16384) ? (long)b * 2048 : (long)(b - 16384) * 2048;
        long e = base + (long)threadIdx.x * 8;
        int s = (int)(e >> 12);
        int k = (int)(e & 4095);
        const float4* p = (const float4*)(src + e);
        float4 v0 = p[0], v1 = p[1];
        union { __hip_bfloat16 h[8]; short8 v; } u;
        u.h[0] = __float2bfloat16(v0.x); u.h[1] = __float2bfloat16(v0.y);
        u.h[2] = __float2bfloat16(v0.z); u.h[3] = __float2bfloat16(v0.w);
        u.h[4] = __float2bfloat16(v1.x); u.h[5] = __float2bfloat16(v1.y);
        u.h[6] = __float2bfloat16(v1.z); u.h[7] = __float2bfloat16(v1.w);
        *(short8*)(dst + (size_t)s * KAUG + k) = u.v;
    } else if (b < 26624) {   // B tail: waug[n][4096 + l*16 + r] = B0[l][n][r]
        int t = (b - 24576) * 256 + threadIdx.x;
        int n = t >> 7, c = t & 127;
        int l = c >> 4, r = c & 15;
        waug[(size_t)n * KAUG + 4096 + c] =
            __float2bfloat16(B0[((size_t)l * DOUT + n) * RLORA + r]);
    } else {                  // A cvt: 128*4096 elems, 8/thread
        long e = ((long)(b - 26624) * 256 + threadIdx.x) * 8;
        const float4* p = (const float4*)(A + e);
        float4 v0 = p[0], v1 = p[1];
        union { __hip_bfloat16 h[8]; short8 v; } u;
        u.h[0] = __float2bfloat16(v0.x); u.h[1] = __float2bfloat16(v0.y);
        u.h[2] = __float2bfloat16(v0.z); u.h[3] = __float2bfloat16(v0.w);
        u.h[4] = __float2bfloat16(v1.x); u.h[5] = __float2bfloat16(v1.y);
        u.h[6] = __float2bfloat16(v1.z); u.h[7] = __float2bfloat16(v1.w);
        *(short8*)(abf + e) = u.v;
    }
}

// ---------- XA_all split-K mini-GEMM: part[kc][8192][128] = Xa[:, kc*1024:+1024] @ Ab^T ----------
__global__ __launch_bounds__(256) void xa_gemm(const __hip_bfloat16* __restrict__ Xa,
                                               const __hip_bfloat16* __restrict__ Ab,
                                               float* __restrict__ part) {
    __shared__ __attribute__((aligned(16))) char sm[32768];
    char* Xs = sm;              // [128][64] bf16
    char* As = sm + 16384;      // [128][64] bf16
    const int tid = threadIdx.x, lane = tid & 63, wave = tid >> 6;
    const int mt = blockIdx.x >> 2, kc = blockIdx.x & 3;
    const int row0 = mt * 128, k0 = kc * 1024;
    const int sr = tid >> 3;                 // 0..31
    const int cp = (tid & 7) ^ (sr & 7);
    const __hip_bfloat16* gX = Xa + (size_t)(row0 + sr) * KAUG + k0 + cp * 8;
    const __hip_bfloat16* gA = Ab + (size_t)sr * DIN + k0 + cp * 8;
    const int lr = lane & 15, lk = lane >> 4;
    f32x4 acc[2][8] = {};
    for (int kt = 0; kt < 16; ++kt) {
        #pragma unroll
        for (int i = 0; i < 4; ++i) {
            __builtin_amdgcn_global_load_lds((const uint32_t*)(gX + (size_t)(32 * i) * KAUG + kt * 64),
                                             (uint32_t*)(Xs + i * 4096 + tid * 16), 16, 0, 0);
            __builtin_amdgcn_global_load_lds((const uint32_t*)(gA + (size_t)(32 * i) * DIN + kt * 64),
                                             (uint32_t*)(As + i * 4096 + tid * 16), 16, 0, 0);
        }
        __syncthreads();
        #pragma unroll
        for (int kk = 0; kk < 2; ++kk) {
            short8 av[2], bv[8];
            #pragma unroll
            for (int m = 0; m < 2; ++m) {
                int row = wave * 32 + m * 16 + lr;
                int cc = (kk * 4 + lk) ^ (row & 7);
                av[m] = *(const short8*)(Xs + row * 128 + cc * 16);
            }
            #pragma unroll
            for (int n = 0; n < 8; ++n) {
                int row = n * 16 + lr;
                int cc = (kk * 4 + lk) ^ (row & 7);
                bv[n] = *(const short8*)(As + row * 128 + cc * 16);
            }
            #pragma unroll
            for (int m = 0; m < 2; ++m)
                #pragma unroll
                for (int n = 0; n < 8; ++n)
                    acc[m][n] = __builtin_amdgcn_mfma_f32_16x16x32_bf16(av[m], bv[n], acc[m][n], 0, 0, 0);
        }
        __syncthreads();
    }
    #pragma unroll
    for (int n = 0; n < 8; ++n) {
        int col = n * 16 + lr;
        #pragma unroll
        for (int m = 0; m < 2; ++m) {
            int r0 = wave * 32 + m * 16 + lk * 4;
            #pragma unroll
            for (int j = 0; j < 4; ++j)
                part[((size_t)kc << 20) + (size_t)(row0 + r0 + j) * 128 + col] = acc[m][n][j];
        }
    }
}

// ---------- reduce split-K partials, mask by adapter, scale, cvt -> xaug tail ----------
__global__ void xa_reduce(const float* __restrict__ part, const int* __restrict__ widx,
                          __hip_bfloat16* __restrict__ xaug) {
    int t = blockIdx.x * 256 + threadIdx.x;   // < 8192*128
    int s = t >> 7, c = t & 127;
    float sum = part[t] + part[(1 << 20) + t] + part[(2 << 20) + t] + part[(3 << 20) + t];
    int l = widx[s];
    float v = ((c >> 4) == l) ? 2.0f * sum : 0.0f;
    xaug[(size_t)s * KAUG + 4096 + c] = __float2bfloat16(v);
}

// ---------- 256x256 GEMM: R11 single-barrier drift skeleton + 32x32x16 MFMA ----------
// 8 waves (2M x 4N), per-wave 128x64 = 4 mtiles x 2 ntiles of 32x32, BK=64,
// LDS 128KB double-buffered. Phase p: {STAGE | [vmcnt(2) @P4,P8] | ds_reads(p) |
// BAR | lgkmcnt(0)+sched_barrier(0) | setprio(1) 8x mfma_32x32x16 setprio(0)}.
// Sync proof carried verbatim from R11 (identical STAGE/read/VM2/BAR sequence;
// only fragment geometry changed):
//  WAR: stage(R)@p >= lastread(R)+2 for all regions (same map).
//  RAW: VM2@P4 drains buf1 (8 oldest of 10); VM2@P8 drains buf0.
// 32x32 pipe: 2495 TF vs 2075 for 16x16 -> MFMA floor 621->517 cyc/phase.
// Frag layouts correctness-verified in R4 (passed absmax 0.03125).
__global__ __launch_bounds__(512, 2) void gemm8(const __hip_bfloat16* __restrict__ Xa,
                                                const __hip_bfloat16* __restrict__ Wa,
                                                const float* __restrict__ bias,
                                                float* __restrict__ out) {
    // layout: buf0.A [0,32K) buf0.B [32K,64K) buf1.A [64K,96K) buf1.B [96K,128K)
    __shared__ __attribute__((aligned(16))) char lds[131072];

    const int tid = threadIdx.x;
    const int lane = tid & 63, wave = tid >> 6;
    const int wm = wave >> 2, wn = wave & 3;
    const int l31 = lane & 31, lhi = lane >> 5;

    // bijective XCD swizzle (512 blocks, 512 % 8 == 0)
    int wg = blockIdx.x;
    int swz = (wg & 7) * 64 + (wg >> 3);
    int bm = swz >> 4, bn = swz & 15;
    const int rowA0 = bm * 256, colB0 = bn * 256;

    // staging: linear LDS dest, inverse-swizzled global source (rule #21).
    // LDS[r][c16] = G[r][c16 ^ (r&7)]
    const int sr = tid >> 3;
    const int cp = (tid & 7) ^ (sr & 7);
    const __hip_bfloat16* srcA = Xa + (size_t)(rowA0 + sr) * KAUG + cp * 8;
    const __hip_bfloat16* srcB = Wa + (size_t)(colB0 + sr) * KAUG + cp * 8;
    char* const stgd = lds + tid * 16;

    auto STAGE = [&](int buf, int mat, int half, int kt) {
        const __hip_bfloat16* s0 = (mat ? srcB : srcA) + (size_t)(half * 128) * KAUG + kt * 64;
        char* d = stgd + buf * 65536 + mat * 32768 + half * 16384;
        __builtin_amdgcn_global_load_lds((const uint32_t*)s0, (uint32_t*)d, 16, 0, 0);
        __builtin_amdgcn_global_load_lds((const uint32_t*)(s0 + (size_t)64 * KAUG),
                                         (uint32_t*)(d + 8192), 16, 0, 0);
    };

    f32x16 acc[4][2] = {};          // [mtile][ntile], 32x32 each
    short8 a[4], b0[4], b1[4];      // a: [mt*2+s] for one (mh, ks-half); b: [nt*2+s]

    // A-frag: lane reads A[row = wm*128 + (mh*2+mt)*32 + l31][k = ks*16 + lhi*8 ..+8]
    // byte chunk = ks*2 + lhi, swizzled by ^(row&7) = ^(l31&7). ks = h*2+s.
    auto LDA_K = [&](short8 (&af)[4], int buf, int mh, int h) {
        const char* base = lds + buf * 65536;
        #pragma unroll
        for (int mt = 0; mt < 2; ++mt)
            #pragma unroll
            for (int s = 0; s < 2; ++s) {
                int row = wm * 128 + (mh * 2 + mt) * 32 + l31;
                int cc = ((h * 2 + s) * 2 + lhi) ^ (row & 7);
                af[mt * 2 + s] = *(const short8*)(base + row * 128 + cc * 16);
            }
    };
    // B-frag: lane reads W[col-row = wn*64 + nt*32 + l31][same k chunks]
    auto LDB_K = [&](short8 (&bf)[4], int buf, int h) {
        const char* base = lds + buf * 65536 + 32768;
        #pragma unroll
        for (int nt = 0; nt < 2; ++nt)
            #pragma unroll
            for (int s = 0; s < 2; ++s) {
                int row = wn * 64 + nt * 32 + l31;
                int cc = ((h * 2 + s) * 2 + lhi) ^ (row & 7);
                bf[nt * 2 + s] = *(const short8*)(base + row * 128 + cc * 16);
            }
    };

// BAR, then drain-all + fence (rule #18), then 8 uninterrupted 32x32 MFMAs.
#define MMQ(AF, BF, MB)                                                            \
    do {                                                                           \
        __builtin_amdgcn_s_barrier();                                              \
        asm volatile("s_waitcnt lgkmcnt(0)" ::: "memory");                         \
        __builtin_amdgcn_sched_barrier(0);                                         \
        __builtin_amdgcn_s_setprio(1);                                             \
        _Pragma("unroll")                                                          \
        for (int s = 0; s < 2; ++s)                                                \
            _Pragma("unroll")                                                      \
            for (int mt = 0; mt < 2; ++mt)                                         \
                _Pragma("unroll")                                                  \
                for (int nt = 0; nt < 2; ++nt)                                     \
                    acc[(MB) + mt][nt] = __builtin_amdgcn_mfma_f32_32x32x16_bf16(  \
                        AF[mt * 2 + s], BF[nt * 2 + s], acc[(MB) + mt][nt], 0, 0, 0); \
        __builtin_amdgcn_s_setprio(0);                                             \
    } while (0)

#define VM2() asm volatile("s_waitcnt vmcnt(2)" ::: "memory")

    // prologue: buf0 <- t0 (8 loads); buf1.B.h0 <- t1 (2 loads); drain buf0.
    STAGE(0, 0, 0, 0); STAGE(0, 0, 1, 0);
    STAGE(0, 1, 0, 0); STAGE(0, 1, 1, 0);
    STAGE(1, 1, 0, 1);
    VM2();   // buf0's 8 landed; 2 (1B.h0) in flight == steady-state entry to P1
    __builtin_amdgcn_s_barrier();

    #pragma unroll 1
    for (int i = 0; i < NT / 2; ++i) {
        int t1 = 2 * i + 1;
        int t2 = 2 * i + 2; if (t2 > NT - 1) t2 = NT - 1;   // clamp keeps vmcnt uniform
        int t3 = 2 * i + 3; if (t3 > NT - 1) t3 = NT - 1;
        // P1: stage 1B.h1<-t1; reads buf0 (A mh0 h0 + B h0); BAR; MMQ mtiles0-1
        STAGE(1, 1, 1, t1);
        LDA_K(a, 0, 0, 0); LDB_K(b0, 0, 0);
        MMQ(a, b0, 0);
        // P2: stage 1A.h0<-t1; reads buf0 (A mh0 h1 + B h1)
        STAGE(1, 0, 0, t1);
        LDA_K(a, 0, 0, 1); LDB_K(b1, 0, 1);
        MMQ(a, b1, 0);
        // P3: stage 1A.h1<-t1; reads buf0 (A mh1 h0); b0 reused from regs
        STAGE(1, 0, 1, t1);
        LDA_K(a, 0, 1, 0);
        MMQ(a, b0, 2);
        // P4: stage 0B.h0<-t2; vmcnt(2) drains buf1 (P8prev+P1+P2+P3 = 8 oldest of 10)
        STAGE(0, 1, 0, t2);
        VM2();
        LDA_K(a, 0, 1, 1);
        MMQ(a, b1, 2);
        // P5: stage 0B.h1<-t2; reads buf1 (A mh0 h0 + B h0)
        STAGE(0, 1, 1, t2);
        LDA_K(a, 1, 0, 0); LDB_K(b0, 1, 0);
        MMQ(a, b0, 0);
        // P6: stage 0A.h0<-t2; reads buf1 (A mh0 h1 + B h1)
        STAGE(0, 0, 0, t2);
        LDA_K(a, 1, 0, 1); LDB_K(b1, 1, 1);
        MMQ(a, b1, 0);
        // P7: stage 0A.h1<-t2; reads buf1 (A mh1 h0)
        STAGE(0, 0, 1, t2);
        LDA_K(a, 1, 1, 0);
        MMQ(a, b0, 2);
        // P8: stage 1B.h0<-t3; vmcnt(2) drains buf0 (P4..P7 = 8 oldest of 10)
        STAGE(1, 1, 0, t3);
        VM2();
        LDA_K(a, 1, 1, 1);
        MMQ(a, b1, 2);
    }

    // epilogue: 32x32 C/D map col=lane&31, row=(r&3)+8*(r>>2)+4*(lane>>5)  [m74/m101]
    #pragma unroll
    for (int nt = 0; nt < 2; ++nt) {
        int col = colB0 + wn * 64 + nt * 32 + l31;
        float bv = bias[col];
        #pragma unroll
        for (int mt = 0; mt < 4; ++mt) {
            int rbase = rowA0 + wm * 128 + mt * 32 + 4 * lhi;
            #pragma unroll
            for (int r = 0; r < 16; ++r) {
                int row = rbase + (r & 3) + 8 * (r >> 2);
                out[(size_t)row * DOUT + col] = acc[mt][nt][r] + bv;
            }
        }
    }
#undef MMQ
#undef VM2
}

extern "C" void kernel_launch(void* const* d_in, const int* in_sizes, int n_in,
                              void* d_out, int out_size, void* d_ws, size_t ws_size,
                              hipStream_t stream) {
    const float* x      = (const float*)d_in[0];
    const float* weight = (const float*)d_in[1];
    const float* bias   = (const float*)d_in[2];
    const float* A_buf  = (const float*)d_in[3];
    const float* B_buf  = (const float*)d_in[4];
    const int*   widx   = (const int*)d_in[5];
    float* out = (float*)d_out;

    __hip_bfloat16* xaug = (__hip_bfloat16*)d_ws;                                    // [8192][4224]
    __hip_bfloat16* waug = (__hip_bfloat16*)((char*)d_ws + (size_t)SDIM * KAUG * 2); // [4096][4224]
    // d_out doubles as scratch before gemm8 overwrites it:
    __hip_bfloat16* abf  = (__hip_bfloat16*)d_out;                    // [128][4096] bf16 = 1MB
    float*          part = (float*)((char*)d_out + (1 << 20));        // [4][8192][128] f32 = 16MB

    // fused prep: x->bf16, W->bf16, B-tail, A->bf16
    prep_all<<<26880, 256, 0, stream>>>(x, weight, B_buf, A_buf, xaug, waug, abf);
    // XA_all partials (split-K x4)
    xa_gemm<<<64 * 4, 256, 0, stream>>>(xaug, abf, part);
    // reduce + adapter mask + scale -> xaug tail
    xa_reduce<<<(SDIM * 128) / 256, 256, 0, stream>>>(part, widx, xaug);
    // 256^2 GEMM (32x32 MFMA) + bias
    gemm8<<<(SDIM / 256) * (DOUT / 256), 512, 0, stream>>>(xaug, waug, bias, out);
}

// Round 14
// 306.204 us; speedup vs baseline: 1.0962x; 1.0962x over previous
//
#include <hip/hip_runtime.h>
#include <hip/hip_bf16.h>
#include <cstdint>

#define SDIM 8192
#define DIN  4096
#define DOUT 4096
#define KAUG 4224   // 4096 + 8*16 LoRA extension
#define NADP 8
#define RLORA 16
#define NT 66       // K-tiles of 64

typedef __attribute__((ext_vector_type(8))) short short8;
typedef __attribute__((ext_vector_type(4))) float f32x4;

// ---------- fused prep: x->bf16, W->bf16, B-tail, A->bf16 in ONE launch ----------
__global__ __launch_bounds__(256) void prep_all(const float* __restrict__ x,
                         const float* __restrict__ W,
                         const float* __restrict__ B0,
                         const float* __restrict__ A,
                         __hip_bfloat16* __restrict__ xaug,
                         __hip_bfloat16* __restrict__ waug,
                         __hip_bfloat16* __restrict__ abf) {
    int b = blockIdx.x;
    if (b < 24576) {   // x or W conversion
        const float* src = (b < 16384) ? x : W;
        __hip_bfloat16* dst = (b < 16384) ? xaug : waug;
        long base = (b < 16384) ? (long)b * 2048 : (long)(b - 16384) * 2048;
        long e = base + (long)threadIdx.x * 8;
        int s = (int)(e >> 12);
        int k = (int)(e & 4095);
        const float4* p = (const float4*)(src + e);
        float4 v0 = p[0], v1 = p[1];
        union { __hip_bfloat16 h[8]; short8 v; } u;
        u.h[0] = __float2bfloat16(v0.x); u.h[1] = __float2bfloat16(v0.y);
        u.h[2] = __float2bfloat16(v0.z); u.h[3] = __float2bfloat16(v0.w);
        u.h[4] = __float2bfloat16(v1.x); u.h[5] = __float2bfloat16(v1.y);
        u.h[6] = __float2bfloat16(v1.z); u.h[7] = __float2bfloat16(v1.w);
        *(short8*)(dst + (size_t)s * KAUG + k) = u.v;
    } else if (b < 26624) {   // B tail: waug[n][4096 + l*16 + r] = B0[l][n][r]
        int t = (b - 24576) * 256 + threadIdx.x;
        int n = t >> 7, c = t & 127;
        int l = c >> 4, r = c & 15;
        waug[(size_t)n * KAUG + 4096 + c] =
            __float2bfloat16(B0[((size_t)l * DOUT + n) * RLORA + r]);
    } else {                  // A cvt: 128*4096 elems, 8/thread
        long e = ((long)(b - 26624) * 256 + threadIdx.x) * 8;
        const float4* p = (const float4*)(A + e);
        float4 v0 = p[0], v1 = p[1];
        union { __hip_bfloat16 h[8]; short8 v; } u;
        u.h[0] = __float2bfloat16(v0.x); u.h[1] = __float2bfloat16(v0.y);
        u.h[2] = __float2bfloat16(v0.z); u.h[3] = __float2bfloat16(v0.w);
        u.h[4] = __float2bfloat16(v1.x); u.h[5] = __float2bfloat16(v1.y);
        u.h[6] = __float2bfloat16(v1.z); u.h[7] = __float2bfloat16(v1.w);
        *(short8*)(abf + e) = u.v;
    }
}

// ---------- XA_all split-K mini-GEMM: part[kc][8192][128] = Xa[:, kc*1024:+1024] @ Ab^T ----------
__global__ __launch_bounds__(256) void xa_gemm(const __hip_bfloat16* __restrict__ Xa,
                                               const __hip_bfloat16* __restrict__ Ab,
                                               float* __restrict__ part) {
    __shared__ __attribute__((aligned(16))) char sm[32768];
    char* Xs = sm;              // [128][64] bf16
    char* As = sm + 16384;      // [128][64] bf16
    const int tid = threadIdx.x, lane = tid & 63, wave = tid >> 6;
    const int mt = blockIdx.x >> 2, kc = blockIdx.x & 3;
    const int row0 = mt * 128, k0 = kc * 1024;
    const int sr = tid >> 3;                 // 0..31
    const int cp = (tid & 7) ^ (sr & 7);
    const __hip_bfloat16* gX = Xa + (size_t)(row0 + sr) * KAUG + k0 + cp * 8;
    const __hip_bfloat16* gA = Ab + (size_t)sr * DIN + k0 + cp * 8;
    const int lr = lane & 15, lk = lane >> 4;
    f32x4 acc[2][8] = {};
    for (int kt = 0; kt < 16; ++kt) {
        #pragma unroll
        for (int i = 0; i < 4; ++i) {
            __builtin_amdgcn_global_load_lds((const uint32_t*)(gX + (size_t)(32 * i) * KAUG + kt * 64),
                                             (uint32_t*)(Xs + i * 4096 + tid * 16), 16, 0, 0);
            __builtin_amdgcn_global_load_lds((const uint32_t*)(gA + (size_t)(32 * i) * DIN + kt * 64),
                                             (uint32_t*)(As + i * 4096 + tid * 16), 16, 0, 0);
        }
        __syncthreads();
        #pragma unroll
        for (int kk = 0; kk < 2; ++kk) {
            short8 av[2], bv[8];
            #pragma unroll
            for (int m = 0; m < 2; ++m) {
                int row = wave * 32 + m * 16 + lr;
                int cc = (kk * 4 + lk) ^ (row & 7);
                av[m] = *(const short8*)(Xs + row * 128 + cc * 16);
            }
            #pragma unroll
            for (int n = 0; n < 8; ++n) {
                int row = n * 16 + lr;
                int cc = (kk * 4 + lk) ^ (row & 7);
                bv[n] = *(const short8*)(As + row * 128 + cc * 16);
            }
            #pragma unroll
            for (int m = 0; m < 2; ++m)
                #pragma unroll
                for (int n = 0; n < 8; ++n)
                    acc[m][n] = __builtin_amdgcn_mfma_f32_16x16x32_bf16(av[m], bv[n], acc[m][n], 0, 0, 0);
        }
        __syncthreads();
    }
    #pragma unroll
    for (int n = 0; n < 8; ++n) {
        int col = n * 16 + lr;
        #pragma unroll
        for (int m = 0; m < 2; ++m) {
            int r0 = wave * 32 + m * 16 + lk * 4;
            #pragma unroll
            for (int j = 0; j < 4; ++j)
                part[((size_t)kc << 20) + (size_t)(row0 + r0 + j) * 128 + col] = acc[m][n][j];
        }
    }
}

// ---------- reduce split-K partials, mask by adapter, scale, cvt -> xaug tail ----------
__global__ void xa_reduce(const float* __restrict__ part, const int* __restrict__ widx,
                          __hip_bfloat16* __restrict__ xaug) {
    int t = blockIdx.x * 256 + threadIdx.x;   // < 8192*128
    int s = t >> 7, c = t & 127;
    float sum = part[t] + part[(1 << 20) + t] + part[(2 << 20) + t] + part[(3 << 20) + t];
    int l = widx[s];
    float v = ((c >> 4) == l) ? 2.0f * sum : 0.0f;
    xaug[(size_t)s * KAUG + 4096 + c] = __float2bfloat16(v);
}

// ---------- 256x256 8-phase GEMM, single-barrier drift + counted lgkm waits ----------
// 8 waves (2M x 4N), per-wave 128x64, BK=64, LDS 128KB double-buffered.
// Phase p: {STAGE | [vmcnt(2) @P4,P8] | ds_reads(p): B FIRST then A | BAR |
//   setprio(1) 16xMFMA setprio(0)}  -- counted lgkm waits (compiler-emitted):
// first MFMA waits for 5 of 8 reads; the rest drain under MFMA issue. Reads
// feed same-phase MFMAs -> compiler cannot sink them (dataflow), no fence
// needed. Sync proof identical to R11 (verbatim ledger):
//  WAR: stage(R)@p >= lastread(R)+2 (map: 1B.h1@P1, 1A.h0@P2, 1A.h1@P3,
//   0B.h0@P4, 0B.h1@P5, 0A.h0@P6, 0A.h1@P7, 1B.h0@P8).
//  RAW: VM2@P4 drains buf1 (8 oldest of 10); VM2@P8 drains buf0.
__global__ __launch_bounds__(512, 2) void gemm8(const __hip_bfloat16* __restrict__ Xa,
                                                const __hip_bfloat16* __restrict__ Wa,
                                                const float* __restrict__ bias,
                                                float* __restrict__ out) {
    // layout: buf0.A [0,32K) buf0.B [32K,64K) buf1.A [64K,96K) buf1.B [96K,128K)
    __shared__ __attribute__((aligned(16))) char lds[131072];

    const int tid = threadIdx.x;
    const int lane = tid & 63, wave = tid >> 6;
    const int wm = wave >> 2, wn = wave & 3;
    const int lr = lane & 15, lk = lane >> 4;

    // bijective XCD swizzle (512 blocks, 512 % 8 == 0)
    int wg = blockIdx.x;
    int swz = (wg & 7) * 64 + (wg >> 3);
    int bm = swz >> 4, bn = swz & 15;
    const int rowA0 = bm * 256, colB0 = bn * 256;

    // staging: linear LDS dest, inverse-swizzled global source (rule #21).
    // LDS[r][c16] = G[r][c16 ^ (r&7)]
    const int sr = tid >> 3;
    const int cp = (tid & 7) ^ (sr & 7);
    const __hip_bfloat16* srcA = Xa + (size_t)(rowA0 + sr) * KAUG + cp * 8;
    const __hip_bfloat16* srcB = Wa + (size_t)(colB0 + sr) * KAUG + cp * 8;
    char* const stgd = lds + tid * 16;

    auto STAGE = [&](int buf, int mat, int half, int kt) {
        const __hip_bfloat16* s0 = (mat ? srcB : srcA) + (size_t)(half * 128) * KAUG + kt * 64;
        char* d = stgd + buf * 65536 + mat * 32768 + half * 16384;
        __builtin_amdgcn_global_load_lds((const uint32_t*)s0, (uint32_t*)d, 16, 0, 0);
        __builtin_amdgcn_global_load_lds((const uint32_t*)(s0 + (size_t)64 * KAUG),
                                         (uint32_t*)(d + 8192), 16, 0, 0);
    };

    // hoisted ds_read bases: row&7 == lane&7 for every fragment row.
    const char* adrA[2][2];
    const char* adrB[2][2];
    #pragma unroll
    for (int kk = 0; kk < 2; ++kk) {
        int ccx = ((kk * 4 + lk) ^ (lane & 7)) * 16;
        adrA[0][kk] = lds + (wm * 128 + lr) * 128 + ccx;
        adrB[0][kk] = lds + 32768 + (wn * 64 + lr) * 128 + ccx;
        adrA[1][kk] = adrA[0][kk] + 65536;
        adrB[1][kk] = adrB[0][kk] + 65536;
    }

    f32x4 acc[8][4] = {};
    short8 a[4], b0[4], b1[4];

    auto LDA_K = [&](short8 (&af)[4], int buf, int mh, int kk) {
        const char* a0 = adrA[buf][kk] + mh * 8192;
        #pragma unroll
        for (int m = 0; m < 4; ++m)
            af[m] = *(const short8*)(a0 + m * 2048);
    };
    auto LDB_K = [&](short8 (&bf)[4], int buf, int kk) {
        const char* b0p = adrB[buf][kk];
        #pragma unroll
        for (int n = 0; n < 4; ++n)
            bf[n] = *(const short8*)(b0p + n * 2048);
    };

// BAR, then 16 MFMAs with compiler-counted lgkm waits (no drain-all, no fence).
#define MMQ(AF, BF, MB)                                                            \
    do {                                                                           \
        __builtin_amdgcn_s_barrier();                                              \
        __builtin_amdgcn_s_setprio(1);                                             \
        _Pragma("unroll")                                                          \
        for (int m = 0; m < 4; ++m)                                                \
            _Pragma("unroll")                                                      \
            for (int n = 0; n < 4; ++n)                                            \
                acc[(MB) + m][n] = __builtin_amdgcn_mfma_f32_16x16x32_bf16(        \
                    AF[m], BF[n], acc[(MB) + m][n], 0, 0, 0);                      \
        __builtin_amdgcn_s_setprio(0);                                             \
    } while (0)

#define VM2() asm volatile("s_waitcnt vmcnt(2)" ::: "memory")

    // prologue: buf0 <- t0 (8 loads); buf1.B.h0 <- t1 (2 loads); drain buf0.
    STAGE(0, 0, 0, 0); STAGE(0, 0, 1, 0);
    STAGE(0, 1, 0, 0); STAGE(0, 1, 1, 0);
    STAGE(1, 1, 0, 1);
    VM2();   // buf0's 8 landed; 2 (1B.h0) in flight == steady-state entry to P1
    __builtin_amdgcn_s_barrier();

    #pragma unroll 1
    for (int i = 0; i < NT / 2; ++i) {
        int t1 = 2 * i + 1;
        int t2 = 2 * i + 2; if (t2 > NT - 1) t2 = NT - 1;   // clamp keeps vmcnt uniform
        int t3 = 2 * i + 3; if (t3 > NT - 1) t3 = NT - 1;
        // P1: stage 1B.h1<-t1; reads buf0 (B kk0 first, then A mh0 kk0); BAR; MMQ
        STAGE(1, 1, 1, t1);
        LDB_K(b0, 0, 0); LDA_K(a, 0, 0, 0);
        MMQ(a, b0, 0);
        // P2: stage 1A.h0<-t1; reads buf0 (B kk1, A mh0 kk1)
        STAGE(1, 0, 0, t1);
        LDB_K(b1, 0, 1); LDA_K(a, 0, 0, 1);
        MMQ(a, b1, 0);
        // P3: stage 1A.h1<-t1; reads buf0 (A mh1 kk0); b0 reused from regs
        STAGE(1, 0, 1, t1);
        LDA_K(a, 0, 1, 0);
        MMQ(a, b0, 4);
        // P4: stage 0B.h0<-t2; vmcnt(2) drains buf1 (P8prev+P1+P2+P3 = 8 oldest of 10)
        STAGE(0, 1, 0, t2);
        VM2();
        LDA_K(a, 0, 1, 1);
        MMQ(a, b1, 4);
        // P5: stage 0B.h1<-t2; reads buf1 (B kk0, A mh0 kk0)
        STAGE(0, 1, 1, t2);
        LDB_K(b0, 1, 0); LDA_K(a, 1, 0, 0);
        MMQ(a, b0, 0);
        // P6: stage 0A.h0<-t2; reads buf1 (B kk1, A mh0 kk1)
        STAGE(0, 0, 0, t2);
        LDB_K(b1, 1, 1); LDA_K(a, 1, 0, 1);
        MMQ(a, b1, 0);
        // P7: stage 0A.h1<-t2; reads buf1 (A mh1 kk0)
        STAGE(0, 0, 1, t2);
        LDA_K(a, 1, 1, 0);
        MMQ(a, b0, 4);
        // P8: stage 1B.h0<-t3; vmcnt(2) drains buf0 (P4..P7 = 8 oldest of 10)
        STAGE(1, 1, 0, t3);
        VM2();
        LDA_K(a, 1, 1, 1);
        MMQ(a, b1, 4);
    }

    // epilogue: C/D map col=lane&15, row=(lane>>4)*4+j  [m89]
    #pragma unroll
    for (int n = 0; n < 4; ++n) {
        int col = colB0 + wn * 64 + n * 16 + lr;
        float bv = bias[col];
        #pragma unroll
        for (int m = 0; m < 8; ++m) {
            int row0 = rowA0 + wm * 128 + m * 16 + lk * 4;
            #pragma unroll
            for (int j = 0; j < 4; ++j) {
                out[(size_t)(row0 + j) * DOUT + col] = acc[m][n][j] + bv;
            }
        }
    }
#undef MMQ
#undef VM2
}

extern "C" void kernel_launch(void* const* d_in, const int* in_sizes, int n_in,
                              void* d_out, int out_size, void* d_ws, size_t ws_size,
                              hipStream_t stream) {
    const float* x      = (const float*)d_in[0];
    const float* weight = (const float*)d_in[1];
    const float* bias   = (const float*)d_in[2];
    const float* A_buf  = (const float*)d_in[3];
    const float* B_buf  = (const float*)d_in[4];
    const int*   widx   = (const int*)d_in[5];
    float* out = (float*)d_out;

    __hip_bfloat16* xaug = (__hip_bfloat16*)d_ws;                                    // [8192][4224]
    __hip_bfloat16* waug = (__hip_bfloat16*)((char*)d_ws + (size_t)SDIM * KAUG * 2); // [4096][4224]
    // d_out doubles as scratch before gemm8 overwrites it:
    __hip_bfloat16* abf  = (__hip_bfloat16*)d_out;                    // [128][4096] bf16 = 1MB
    float*          part = (float*)((char*)d_out + (1 << 20));        // [4][8192][128] f32 = 16MB

    // fused prep: x->bf16, W->bf16, B-tail, A->bf16
    prep_all<<<26880, 256, 0, stream>>>(x, weight, B_buf, A_buf, xaug, waug, abf);
    // XA_all partials (split-K x4)
    xa_gemm<<<64 * 4, 256, 0, stream>>>(xaug, abf, part);
    // reduce + adapter mask + scale -> xaug tail
    xa_reduce<<<(SDIM * 128) / 256, 256, 0, stream>>>(part, widx, xaug);
    // 8-phase 256^2 GEMM + bias
    gemm8<<<(SDIM / 256) * (DOUT / 256), 512, 0, stream>>>(xaug, waug, bias, out);
}